// Round 4
// baseline (223.888 us; speedup 1.0000x reference)
//
#include <hip/hip_runtime.h>
#include <hip/hip_bf16.h>
#include <stdint.h>
#include <stddef.h>

typedef short bf16x8 __attribute__((ext_vector_type(8)));
typedef float f32x4 __attribute__((ext_vector_type(4)));

#define HW 4096
#define WDIM 64

__device__ __forceinline__ short f2bf(float f) {
  union { __hip_bfloat16 b; short s; } u;
  u.b = __float2bfloat16(f);
  return u.s;
}
__device__ __forceinline__ float bf2f(short s) {
  union { unsigned u; float f; } u;
  u.u = ((unsigned)(unsigned short)s) << 16;
  return u.f;
}

// ---------------- prep: gather/convert weights (hi/lo split) + bias ----------------
__global__ void prep_weights(const float* __restrict__ w0, const float* __restrict__ w1,
                             const float* __restrict__ w2, const float* __restrict__ b0,
                             const float* __restrict__ b1, const float* __restrict__ b2,
                             const float* __restrict__ pw,
                             short* __restrict__ Wh, short* __restrict__ Wl,
                             short* __restrict__ Ph, short* __restrict__ Pl,
                             float* __restrict__ bias_sel) {
  int idx = blockIdx.x * 256 + threadIdx.x;
  if (idx < 768 * 256) {
    int j = idx >> 8;
    int h = (j & 255) >> 5;
    const float* w = (h < 4) ? w0 : ((h < 7) ? w1 : w2);
    float v = w[idx];
    short hi = f2bf(v);
    Wh[idx] = hi;
    Wl[idx] = f2bf(v - bf2f(hi));
  } else if (idx < 768 * 256 + 256 * 256) {
    int k = idx - 768 * 256;
    float v = pw[k];
    short hi = f2bf(v);
    Ph[k] = hi;
    Pl[k] = f2bf(v - bf2f(hi));
  } else if (idx < 768 * 256 + 256 * 256 + 768) {
    int j = idx - (768 * 256 + 256 * 256);
    int h = (j & 255) >> 5;
    const float* bb = (h < 4) ? b0 : ((h < 7) ? b1 : b2);
    bias_sel[j] = bb[j];
  }
}

// ---------------- transpose x: (B,256,HW) f32 -> XT (B,HW,256) bf16 hi/lo ----------------
__global__ void transpose_x(const float* __restrict__ x, short* __restrict__ XTh,
                            short* __restrict__ XTl) {
  __shared__ float tile[32][33];
  int b = blockIdx.z;
  int p0 = blockIdx.x * 32, c0 = blockIdx.y * 32;
  int tx = threadIdx.x, ty = threadIdx.y;       // 32 x 8
  const float* xb = x + (size_t)b * 256 * HW;
  #pragma unroll
  for (int i = 0; i < 32; i += 8)
    tile[ty + i][tx] = xb[(size_t)(c0 + ty + i) * HW + p0 + tx];
  __syncthreads();
  size_t ob = (size_t)b * HW * 256;
  #pragma unroll
  for (int i = 0; i < 32; i += 8) {
    float v = tile[tx][ty + i];
    short hi = f2bf(v);
    size_t o = ob + (size_t)(p0 + ty + i) * 256 + c0 + tx;
    XTh[o] = hi;
    XTl[o] = f2bf(v - bf2f(hi));
  }
}

// ---------------- split-bf16 MFMA GEMM ----------------
// OUT=0: write qkv_t layout [b][t(3)][h(8)][p(4096)][d(32)] fp32 (float4 stores)
// OUT=1: write standard C[b][m][p] fp32
template <int OUT>
__global__ __launch_bounds__(256) void gemm_split(
    const short* __restrict__ Ah, const short* __restrict__ Al,
    const short* __restrict__ Bh, const short* __restrict__ Bl,
    const float* __restrict__ bias, float* __restrict__ C, int M) {
  constexpr int LD = 40;
  __shared__ short Ash[128 * LD], Asl[128 * LD], Bsh[128 * LD], Bsl[128 * LD];
  int tid = threadIdx.x;
  int b = blockIdx.z;
  size_t aoff = (size_t)blockIdx.y * 128 * 256;
  size_t boff = (size_t)b * HW * 256 + (size_t)blockIdx.x * 128 * 256;
  int lane = tid & 63, wid = tid >> 6;
  int wm = wid >> 1, wn = wid & 1;
  int il = lane & 15, kg = lane >> 4;
  f32x4 acc[4][4] = {};
  int row_s = tid >> 2;
  int kk_s = (tid & 3) * 8;

  for (int kt = 0; kt < 256; kt += 32) {
    size_t ga0 = aoff + (size_t)row_s * 256 + kt + kk_s;
    size_t ga1 = aoff + (size_t)(row_s + 64) * 256 + kt + kk_s;
    size_t gb0 = boff + (size_t)row_s * 256 + kt + kk_s;
    size_t gb1 = boff + (size_t)(row_s + 64) * 256 + kt + kk_s;
    bf16x8 rah0 = *(const bf16x8*)&Ah[ga0];
    bf16x8 rah1 = *(const bf16x8*)&Ah[ga1];
    bf16x8 ral0 = *(const bf16x8*)&Al[ga0];
    bf16x8 ral1 = *(const bf16x8*)&Al[ga1];
    bf16x8 rbh0 = *(const bf16x8*)&Bh[gb0];
    bf16x8 rbh1 = *(const bf16x8*)&Bh[gb1];
    bf16x8 rbl0 = *(const bf16x8*)&Bl[gb0];
    bf16x8 rbl1 = *(const bf16x8*)&Bl[gb1];
    __syncthreads();
    *(bf16x8*)&Ash[row_s * LD + kk_s] = rah0;
    *(bf16x8*)&Ash[(row_s + 64) * LD + kk_s] = rah1;
    *(bf16x8*)&Asl[row_s * LD + kk_s] = ral0;
    *(bf16x8*)&Asl[(row_s + 64) * LD + kk_s] = ral1;
    *(bf16x8*)&Bsh[row_s * LD + kk_s] = rbh0;
    *(bf16x8*)&Bsh[(row_s + 64) * LD + kk_s] = rbh1;
    *(bf16x8*)&Bsl[row_s * LD + kk_s] = rbl0;
    *(bf16x8*)&Bsl[(row_s + 64) * LD + kk_s] = rbl1;
    __syncthreads();
    bf16x8 afh[4], afl[4], bfh[4], bfl[4];
    #pragma unroll
    for (int mr = 0; mr < 4; ++mr) {
      int r = (wm * 64 + mr * 16 + il) * LD + kg * 8;
      afh[mr] = *(bf16x8*)&Ash[r];
      afl[mr] = *(bf16x8*)&Asl[r];
    }
    #pragma unroll
    for (int nr = 0; nr < 4; ++nr) {
      int r = (wn * 64 + nr * 16 + il) * LD + kg * 8;
      bfh[nr] = *(bf16x8*)&Bsh[r];
      bfl[nr] = *(bf16x8*)&Bsl[r];
    }
    #pragma unroll
    for (int mr = 0; mr < 4; ++mr)
      #pragma unroll
      for (int nr = 0; nr < 4; ++nr) {
        acc[mr][nr] = __builtin_amdgcn_mfma_f32_16x16x32_bf16(afh[mr], bfh[nr], acc[mr][nr], 0, 0, 0);
        acc[mr][nr] = __builtin_amdgcn_mfma_f32_16x16x32_bf16(afh[mr], bfl[nr], acc[mr][nr], 0, 0, 0);
        acc[mr][nr] = __builtin_amdgcn_mfma_f32_16x16x32_bf16(afl[mr], bfh[nr], acc[mr][nr], 0, 0, 0);
      }
  }

  int m0 = blockIdx.y * 128, n0 = blockIdx.x * 128;
  #pragma unroll
  for (int mr = 0; mr < 4; ++mr) {
    #pragma unroll
    for (int nr = 0; nr < 4; ++nr) {
      int grow0 = m0 + wm * 64 + mr * 16 + kg * 4;
      int gcol = n0 + wn * 64 + nr * 16 + il;
      if (OUT == 0) {
        // qkv_t: [(b*3+t)*8+h][p][d], float4 at (grow0..+3, gcol)
        int t = grow0 >> 8, h = (grow0 >> 5) & 7, d0 = grow0 & 31;
        size_t base = (((size_t)(b * 3 + t) * 8 + h) << 17) + ((size_t)gcol << 5) + d0;
        f32x4 vv;
        #pragma unroll
        for (int r = 0; r < 4; ++r) vv[r] = acc[mr][nr][r] + bias[grow0 + r];
        *(f32x4*)&C[base] = vv;
      } else {
        size_t cbase = (size_t)b * M * HW;
        #pragma unroll
        for (int r = 0; r < 4; ++r)
          C[cbase + (size_t)(grow0 + r) * HW + gcol] = acc[mr][nr][r] + bias[grow0 + r];
      }
    }
  }
}

// ---------------- attention: wave-autonomous, neighbor-split in-wave ----------------
// qkv_t layout: [(b*3+t)*8+h][p][d=32] fp32. Lane = pl + PT_W*g (PT_W=64/GW).
// Partial (denom, acc[32]) over neighbors i = g, g+GW, ...; reduce-scatter butterfly.
template <int KSZ, int DIL, int GW>
__device__ __forceinline__ void attn_wave(const float* __restrict__ qkvt,
                                          short* __restrict__ Yh, short* __restrict__ Yl,
                                          int b, int hq, int p0, int lane) {
  constexpr int R = KSZ / 2;
  constexpr int L = KSZ * KSZ;
  constexpr int PT_W = 64 / GW;
  constexpr int NV = (L + GW - 1) / GW;
  constexpr int LOG2GW = (GW == 4) ? 2 : ((GW == 8) ? 3 : 4);
  constexpr int ND = 32 >> LOG2GW;
  const float SCALE = 0.17677669529663687f;     // 32^-0.5

  int pl = lane & (PT_W - 1);
  int g = lane >> (6 - LOG2GW);
  int p = p0 + pl;
  const float* qrow = qkvt + (((size_t)(b * 24 + hq)) << 17) + ((size_t)p << 5);
  const float* kbase = qkvt + (((size_t)(b * 24 + 8 + hq)) << 17);
  const float* vbase = qkvt + (((size_t)(b * 24 + 16 + hq)) << 17);

  float q[32];
  #pragma unroll
  for (int j = 0; j < 8; ++j) {
    f32x4 t = *(const f32x4*)&qrow[4 * j];
    q[4 * j + 0] = t[0] * SCALE; q[4 * j + 1] = t[1] * SCALE;
    q[4 * j + 2] = t[2] * SCALE; q[4 * j + 3] = t[3] * SCALE;
  }

  float acc[32];
  #pragma unroll
  for (int d = 0; d < 32; ++d) acc[d] = 0.0f;
  float denom = 0.0f;

  int y = p >> 6, x = p & 63;

  #pragma unroll
  for (int ii = 0; ii < NV; ++ii) {
    int i = g + ii * GW;
    if (i < L) {
      int dy = i / KSZ - R;
      int dx = i % KSZ - R;
      int ny = y + dy * DIL, nx = x + dx * DIL;
      if ((unsigned)ny < WDIM && (unsigned)nx < WDIM) {
        int pp = ny * WDIM + nx;
        const float* krow = kbase + ((size_t)pp << 5);
        float s0 = 0.f, s1 = 0.f, s2 = 0.f, s3 = 0.f;
        #pragma unroll
        for (int j = 0; j < 8; ++j) {
          f32x4 kk = *(const f32x4*)&krow[4 * j];
          s0 += q[4 * j + 0] * kk[0];
          s1 += q[4 * j + 1] * kk[1];
          s2 += q[4 * j + 2] * kk[2];
          s3 += q[4 * j + 3] * kk[3];
        }
        float e = __expf((s0 + s1) + (s2 + s3));
        denom += e;
        const float* vrow = vbase + ((size_t)pp << 5);
        #pragma unroll
        for (int j = 0; j < 8; ++j) {
          f32x4 vv = *(const f32x4*)&vrow[4 * j];
          acc[4 * j + 0] += e * vv[0];
          acc[4 * j + 1] += e * vv[1];
          acc[4 * j + 2] += e * vv[2];
          acc[4 * j + 3] += e * vv[3];
        }
      } else {
        denom += 1.0f;                            // zero-padded unfold semantics
      }
    }
  }

  // reduce-scatter across the GW groups (lane bits [6-LOG2GW, 5])
  #pragma unroll
  for (int lev = 0; lev < LOG2GW; ++lev) {
    const int m = 32 >> lev;                      // 32,16,8,4
    const int half = 32 >> (lev + 1);             // floats kept this round
    bool hiSel = (lane & m) != 0;
    denom += __shfl_xor(denom, m);
    #pragma unroll
    for (int j = 0; j < half; ++j) {
      float send = hiSel ? acc[j] : acc[j + half];
      float r = __shfl_xor(send, m);
      acc[j] = (hiSel ? acc[j + half] : acc[j]) + r;
    }
  }

  float inv = 1.0f / denom;
  size_t yo = ((size_t)b * HW + p) * 256 + hq * 32 + g * ND;
  #pragma unroll
  for (int j = 0; j < ND; ++j) {
    float v = acc[j] * inv;
    short hi = f2bf(v);
    Yh[yo + j] = hi;
    Yl[yo + j] = f2bf(v - bf2f(hi));
  }
}

// blocks: [0,512) ksz5 (GW=4, 64p/blk), [512,1280) ksz7 (GW=8, 32p/blk),
//         [1280,1792) ksz9 (GW=16, 16p/blk). 256 thr = 4 independent waves.
__global__ __launch_bounds__(256, 4) void attn_all(const float* __restrict__ qkvt,
                                                   short* __restrict__ Yh,
                                                   short* __restrict__ Yl) {
  int tid = threadIdx.x;
  int lane = tid & 63, wave = tid >> 6;
  int bx = blockIdx.x;
  if (bx < 512) {
    int tile = bx & 63;                           // 64 tiles of 64 p
    int rest = bx >> 6;
    int b = rest & 1, h = rest >> 1;              // h 0..3
    attn_wave<5, 1, 4>(qkvt, Yh, Yl, b, h, tile * 64 + wave * 16, lane);
  } else if (bx < 1280) {
    int s = bx - 512;
    int tile = s & 127;                           // 128 tiles of 32 p
    int rest = s >> 7;
    int b = rest & 1, h = 4 + (rest >> 1);        // h 4..6
    attn_wave<7, 2, 8>(qkvt, Yh, Yl, b, h, tile * 32 + wave * 8, lane);
  } else {
    int s = bx - 1280;
    int tile = s & 255;                           // 256 tiles of 16 p
    int b = s >> 8;                               // h = 7
    attn_wave<9, 3, 16>(qkvt, Yh, Yl, b, 7, tile * 16 + wave * 4, lane);
  }
}

// ---------------- launch ----------------
extern "C" void kernel_launch(void* const* d_in, const int* in_sizes, int n_in,
                              void* d_out, int out_size, void* d_ws, size_t ws_size,
                              hipStream_t stream) {
  const float* x  = (const float*)d_in[0];
  const float* w0 = (const float*)d_in[1];
  const float* b0 = (const float*)d_in[2];
  const float* w1 = (const float*)d_in[3];
  const float* b1 = (const float*)d_in[4];
  const float* w2 = (const float*)d_in[5];
  const float* b2 = (const float*)d_in[6];
  const float* pw = (const float*)d_in[7];
  const float* pb = (const float*)d_in[8];

  char* ws = (char*)d_ws;
  float* qkvt = (float*)ws; ws += (size_t)2 * 768 * HW * 4;   // [b][t][h][p][d]
  short* XTh = (short*)ws;  ws += (size_t)2 * HW * 256 * 2;
  short* XTl = (short*)ws;  ws += (size_t)2 * HW * 256 * 2;
  short* Yh  = (short*)ws;  ws += (size_t)2 * HW * 256 * 2;
  short* Yl  = (short*)ws;  ws += (size_t)2 * HW * 256 * 2;
  short* Wh  = (short*)ws;  ws += (size_t)768 * 256 * 2;
  short* Wl  = (short*)ws;  ws += (size_t)768 * 256 * 2;
  short* Ph  = (short*)ws;  ws += (size_t)256 * 256 * 2;
  short* Pl  = (short*)ws;  ws += (size_t)256 * 256 * 2;
  float* bsel= (float*)ws;  ws += 4096;

  prep_weights<<<1027, 256, 0, stream>>>(w0, w1, w2, b0, b1, b2, pw, Wh, Wl, Ph, Pl, bsel);
  transpose_x<<<dim3(128, 8, 2), dim3(32, 8), 0, stream>>>(x, XTh, XTl);
  gemm_split<0><<<dim3(32, 6, 2), 256, 0, stream>>>(Wh, Wl, XTh, XTl, bsel, qkvt, 768);
  attn_all<<<1792, 256, 0, stream>>>(qkvt, Yh, Yl);
  gemm_split<1><<<dim3(32, 2, 2), 256, 0, stream>>>(Ph, Pl, Yh, Yl, pb, (float*)d_out, 256);
}

// Round 5
// 222.472 us; speedup vs baseline: 1.0064x; 1.0064x over previous
//
#include <hip/hip_runtime.h>
#include <hip/hip_bf16.h>
#include <stdint.h>
#include <stddef.h>

typedef short bf16x8 __attribute__((ext_vector_type(8)));
typedef short s16x8 __attribute__((ext_vector_type(8)));
typedef float f32x4 __attribute__((ext_vector_type(4)));

#define HW 4096
#define WDIM 64

__device__ __forceinline__ short f2bf(float f) {
  union { __hip_bfloat16 b; short s; } u;
  u.b = __float2bfloat16(f);
  return u.s;
}
__device__ __forceinline__ float bf2f(short s) {
  union { unsigned u; float f; } u;
  u.u = ((unsigned)(unsigned short)s) << 16;
  return u.f;
}

// ---------------- prep: gather/convert weights (hi/lo split) + bias ----------------
__global__ void prep_weights(const float* __restrict__ w0, const float* __restrict__ w1,
                             const float* __restrict__ w2, const float* __restrict__ b0,
                             const float* __restrict__ b1, const float* __restrict__ b2,
                             const float* __restrict__ pw,
                             short* __restrict__ Wh, short* __restrict__ Wl,
                             short* __restrict__ Ph, short* __restrict__ Pl,
                             float* __restrict__ bias_sel) {
  int idx = blockIdx.x * 256 + threadIdx.x;
  if (idx < 768 * 256) {
    int j = idx >> 8;
    int h = (j & 255) >> 5;
    const float* w = (h < 4) ? w0 : ((h < 7) ? w1 : w2);
    float v = w[idx];
    short hi = f2bf(v);
    Wh[idx] = hi;
    Wl[idx] = f2bf(v - bf2f(hi));
  } else if (idx < 768 * 256 + 256 * 256) {
    int k = idx - 768 * 256;
    float v = pw[k];
    short hi = f2bf(v);
    Ph[k] = hi;
    Pl[k] = f2bf(v - bf2f(hi));
  } else if (idx < 768 * 256 + 256 * 256 + 768) {
    int j = idx - (768 * 256 + 256 * 256);
    int h = (j & 255) >> 5;
    const float* bb = (h < 4) ? b0 : ((h < 7) ? b1 : b2);
    bias_sel[j] = bb[j];
  }
}

// ---------------- transpose x: (B,256,HW) f32 -> XT (B,HW,256) bf16 hi/lo ----------------
__global__ void transpose_x(const float* __restrict__ x, short* __restrict__ XTh,
                            short* __restrict__ XTl) {
  __shared__ float tile[32][33];
  int b = blockIdx.z;
  int p0 = blockIdx.x * 32, c0 = blockIdx.y * 32;
  int tx = threadIdx.x, ty = threadIdx.y;       // 32 x 8
  const float* xb = x + (size_t)b * 256 * HW;
  #pragma unroll
  for (int i = 0; i < 32; i += 8)
    tile[ty + i][tx] = xb[(size_t)(c0 + ty + i) * HW + p0 + tx];
  __syncthreads();
  size_t ob = (size_t)b * HW * 256;
  #pragma unroll
  for (int i = 0; i < 32; i += 8) {
    float v = tile[tx][ty + i];
    short hi = f2bf(v);
    size_t o = ob + (size_t)(p0 + ty + i) * 256 + c0 + tx;
    XTh[o] = hi;
    XTl[o] = f2bf(v - bf2f(hi));
  }
}

// ---------------- split-bf16 MFMA GEMM ----------------
// OUT=0: write qkv_t layout [b][t(3)][h(8)][p(4096)][d(32)] fp32 (float4 stores)
// OUT=1: write standard C[b][m][p] fp32
template <int OUT>
__global__ __launch_bounds__(256) void gemm_split(
    const short* __restrict__ Ah, const short* __restrict__ Al,
    const short* __restrict__ Bh, const short* __restrict__ Bl,
    const float* __restrict__ bias, float* __restrict__ C, int M) {
  constexpr int LD = 40;
  __shared__ short Ash[128 * LD], Asl[128 * LD], Bsh[128 * LD], Bsl[128 * LD];
  int tid = threadIdx.x;
  int b = blockIdx.z;
  size_t aoff = (size_t)blockIdx.y * 128 * 256;
  size_t boff = (size_t)b * HW * 256 + (size_t)blockIdx.x * 128 * 256;
  int lane = tid & 63, wid = tid >> 6;
  int wm = wid >> 1, wn = wid & 1;
  int il = lane & 15, kg = lane >> 4;
  f32x4 acc[4][4] = {};
  int row_s = tid >> 2;
  int kk_s = (tid & 3) * 8;

  for (int kt = 0; kt < 256; kt += 32) {
    size_t ga0 = aoff + (size_t)row_s * 256 + kt + kk_s;
    size_t ga1 = aoff + (size_t)(row_s + 64) * 256 + kt + kk_s;
    size_t gb0 = boff + (size_t)row_s * 256 + kt + kk_s;
    size_t gb1 = boff + (size_t)(row_s + 64) * 256 + kt + kk_s;
    bf16x8 rah0 = *(const bf16x8*)&Ah[ga0];
    bf16x8 rah1 = *(const bf16x8*)&Ah[ga1];
    bf16x8 ral0 = *(const bf16x8*)&Al[ga0];
    bf16x8 ral1 = *(const bf16x8*)&Al[ga1];
    bf16x8 rbh0 = *(const bf16x8*)&Bh[gb0];
    bf16x8 rbh1 = *(const bf16x8*)&Bh[gb1];
    bf16x8 rbl0 = *(const bf16x8*)&Bl[gb0];
    bf16x8 rbl1 = *(const bf16x8*)&Bl[gb1];
    __syncthreads();
    *(bf16x8*)&Ash[row_s * LD + kk_s] = rah0;
    *(bf16x8*)&Ash[(row_s + 64) * LD + kk_s] = rah1;
    *(bf16x8*)&Asl[row_s * LD + kk_s] = ral0;
    *(bf16x8*)&Asl[(row_s + 64) * LD + kk_s] = ral1;
    *(bf16x8*)&Bsh[row_s * LD + kk_s] = rbh0;
    *(bf16x8*)&Bsh[(row_s + 64) * LD + kk_s] = rbh1;
    *(bf16x8*)&Bsl[row_s * LD + kk_s] = rbl0;
    *(bf16x8*)&Bsl[(row_s + 64) * LD + kk_s] = rbl1;
    __syncthreads();
    bf16x8 afh[4], afl[4], bfh[4], bfl[4];
    #pragma unroll
    for (int mr = 0; mr < 4; ++mr) {
      int r = (wm * 64 + mr * 16 + il) * LD + kg * 8;
      afh[mr] = *(bf16x8*)&Ash[r];
      afl[mr] = *(bf16x8*)&Asl[r];
    }
    #pragma unroll
    for (int nr = 0; nr < 4; ++nr) {
      int r = (wn * 64 + nr * 16 + il) * LD + kg * 8;
      bfh[nr] = *(bf16x8*)&Bsh[r];
      bfl[nr] = *(bf16x8*)&Bsl[r];
    }
    #pragma unroll
    for (int mr = 0; mr < 4; ++mr)
      #pragma unroll
      for (int nr = 0; nr < 4; ++nr) {
        acc[mr][nr] = __builtin_amdgcn_mfma_f32_16x16x32_bf16(afh[mr], bfh[nr], acc[mr][nr], 0, 0, 0);
        acc[mr][nr] = __builtin_amdgcn_mfma_f32_16x16x32_bf16(afh[mr], bfl[nr], acc[mr][nr], 0, 0, 0);
        acc[mr][nr] = __builtin_amdgcn_mfma_f32_16x16x32_bf16(afl[mr], bfh[nr], acc[mr][nr], 0, 0, 0);
      }
  }

  int m0 = blockIdx.y * 128, n0 = blockIdx.x * 128;
  #pragma unroll
  for (int mr = 0; mr < 4; ++mr) {
    #pragma unroll
    for (int nr = 0; nr < 4; ++nr) {
      int grow0 = m0 + wm * 64 + mr * 16 + kg * 4;
      int gcol = n0 + wn * 64 + nr * 16 + il;
      if (OUT == 0) {
        // qkv_t: [(b*3+t)*8+h][p][d], float4 at (grow0..+3, gcol)
        int t = grow0 >> 8, h = (grow0 >> 5) & 7, d0 = grow0 & 31;
        size_t base = (((size_t)(b * 3 + t) * 8 + h) << 17) + ((size_t)gcol << 5) + d0;
        f32x4 vv;
        #pragma unroll
        for (int r = 0; r < 4; ++r) vv[r] = acc[mr][nr][r] + bias[grow0 + r];
        *(f32x4*)&C[base] = vv;
      } else {
        size_t cbase = (size_t)b * M * HW;
        #pragma unroll
        for (int r = 0; r < 4; ++r)
          C[cbase + (size_t)(grow0 + r) * HW + gcol] = acc[mr][nr][r] + bias[grow0 + r];
      }
    }
  }
}

// ---------------- attention: d-split, register-lean ----------------
// qkv_t layout: [(b*3+t)*8+h][p][d=32] fp32. Lane = pl(0..15) + 16*dq(0..3).
// Each lane owns an 8-float d-slice of one position; logits reduced over dq
// lanes via 2 shuffles; denom tracked redundantly per lane (identical values).
template <int KSZ, int DIL>
__device__ __forceinline__ void attn_wave(const float* __restrict__ qkvt,
                                          short* __restrict__ Yh, short* __restrict__ Yl,
                                          int b, int hq, int p0, int lane) {
  constexpr int R = KSZ / 2;
  const float SCALE = 0.17677669529663687f;     // 32^-0.5
  int pl = lane & 15;
  int dq = lane >> 4;                            // 0..3
  int p = p0 + pl;
  const float* qrow = qkvt + (((size_t)(b * 24 + hq)) << 17) + ((size_t)p << 5) + dq * 8;
  const float* kb = qkvt + (((size_t)(b * 24 + 8 + hq)) << 17) + dq * 8;
  const float* vb = qkvt + (((size_t)(b * 24 + 16 + hq)) << 17) + dq * 8;

  f32x4 q0 = *(const f32x4*)&qrow[0];
  f32x4 q1 = *(const f32x4*)&qrow[4];
  #pragma unroll
  for (int j = 0; j < 4; ++j) { q0[j] *= SCALE; q1[j] *= SCALE; }

  f32x4 a0 = {0.f, 0.f, 0.f, 0.f}, a1 = {0.f, 0.f, 0.f, 0.f};
  float denom = 0.f;
  int y = p >> 6, x = p & 63;

  #pragma unroll
  for (int dy = -R; dy <= R; ++dy) {
    int ny = y + dy * DIL;
    #pragma unroll
    for (int dx = -R; dx <= R; ++dx) {
      int nx = x + dx * DIL;
      if ((unsigned)ny < WDIM && (unsigned)nx < WDIM) {
        int pp = ny * WDIM + nx;
        const float* krow = kb + ((size_t)pp << 5);
        f32x4 k0 = *(const f32x4*)&krow[0];
        f32x4 k1 = *(const f32x4*)&krow[4];
        float s = q0[0] * k0[0] + q0[1] * k0[1] + q0[2] * k0[2] + q0[3] * k0[3]
                + q1[0] * k1[0] + q1[1] * k1[1] + q1[2] * k1[2] + q1[3] * k1[3];
        s += __shfl_xor(s, 16);                  // reduce over dq lanes
        s += __shfl_xor(s, 32);
        float e = __expf(s);
        denom += e;
        const float* vrow = vb + ((size_t)pp << 5);
        f32x4 v0 = *(const f32x4*)&vrow[0];
        f32x4 v1 = *(const f32x4*)&vrow[4];
        #pragma unroll
        for (int j = 0; j < 4; ++j) { a0[j] += e * v0[j]; a1[j] += e * v1[j]; }
      } else {
        denom += 1.0f;                           // zero-padded unfold semantics
      }
    }
  }

  float inv = 1.0f / denom;
  size_t yo = ((size_t)b * HW + p) * 256 + hq * 32 + dq * 8;
  s16x8 oh, ol;
  #pragma unroll
  for (int j = 0; j < 4; ++j) {
    float v = a0[j] * inv;
    short hi = f2bf(v);
    oh[j] = hi; ol[j] = f2bf(v - bf2f(hi));
    float w = a1[j] * inv;
    short hi2 = f2bf(w);
    oh[4 + j] = hi2; ol[4 + j] = f2bf(w - bf2f(hi2));
  }
  *(s16x8*)&Yh[yo] = oh;                         // 16B-aligned
  *(s16x8*)&Yl[yo] = ol;
}

// blocks: [0,512) ksz5 (2b x 4h x 64 tiles), [512,896) ksz7 (2b x 3h x 64),
//         [896,1024) ksz9 (2b x 1h x 64). 256 thr = 4 waves x 16 positions.
__global__ __launch_bounds__(256, 8) void attn_all(const float* __restrict__ qkvt,
                                                   short* __restrict__ Yh,
                                                   short* __restrict__ Yl) {
  int tid = threadIdx.x;
  int lane = tid & 63, wave = tid >> 6;
  int bx = blockIdx.x;
  if (bx < 512) {
    int tile = bx & 63;
    int rest = bx >> 6;
    int b = rest & 1, h = rest >> 1;              // h 0..3
    attn_wave<5, 1>(qkvt, Yh, Yl, b, h, tile * 64 + wave * 16, lane);
  } else if (bx < 896) {
    int s = bx - 512;
    int tile = s & 63;
    int rest = s >> 6;
    int b = rest & 1, h = 4 + (rest >> 1);        // h 4..6
    attn_wave<7, 2>(qkvt, Yh, Yl, b, h, tile * 64 + wave * 16, lane);
  } else {
    int s = bx - 896;
    int tile = s & 63;
    int b = s >> 6;                               // h = 7
    attn_wave<9, 3>(qkvt, Yh, Yl, b, 7, tile * 64 + wave * 16, lane);
  }
}

// ---------------- launch ----------------
extern "C" void kernel_launch(void* const* d_in, const int* in_sizes, int n_in,
                              void* d_out, int out_size, void* d_ws, size_t ws_size,
                              hipStream_t stream) {
  const float* x  = (const float*)d_in[0];
  const float* w0 = (const float*)d_in[1];
  const float* b0 = (const float*)d_in[2];
  const float* w1 = (const float*)d_in[3];
  const float* b1 = (const float*)d_in[4];
  const float* w2 = (const float*)d_in[5];
  const float* b2 = (const float*)d_in[6];
  const float* pw = (const float*)d_in[7];
  const float* pb = (const float*)d_in[8];

  char* ws = (char*)d_ws;
  float* qkvt = (float*)ws; ws += (size_t)2 * 768 * HW * 4;   // [b][t][h][p][d]
  short* XTh = (short*)ws;  ws += (size_t)2 * HW * 256 * 2;
  short* XTl = (short*)ws;  ws += (size_t)2 * HW * 256 * 2;
  short* Yh  = (short*)ws;  ws += (size_t)2 * HW * 256 * 2;
  short* Yl  = (short*)ws;  ws += (size_t)2 * HW * 256 * 2;
  short* Wh  = (short*)ws;  ws += (size_t)768 * 256 * 2;
  short* Wl  = (short*)ws;  ws += (size_t)768 * 256 * 2;
  short* Ph  = (short*)ws;  ws += (size_t)256 * 256 * 2;
  short* Pl  = (short*)ws;  ws += (size_t)256 * 256 * 2;
  float* bsel= (float*)ws;  ws += 4096;

  prep_weights<<<1027, 256, 0, stream>>>(w0, w1, w2, b0, b1, b2, pw, Wh, Wl, Ph, Pl, bsel);
  transpose_x<<<dim3(128, 8, 2), dim3(32, 8), 0, stream>>>(x, XTh, XTl);
  gemm_split<0><<<dim3(32, 6, 2), 256, 0, stream>>>(Wh, Wl, XTh, XTl, bsel, qkvt, 768);
  attn_all<<<1024, 256, 0, stream>>>(qkvt, Yh, Yl);
  gemm_split<1><<<dim3(32, 2, 2), 256, 0, stream>>>(Ph, Pl, Yh, Yl, pb, (float*)d_out, 256);
}

// Round 6
// 197.971 us; speedup vs baseline: 1.1309x; 1.1238x over previous
//
#include <hip/hip_runtime.h>
#include <hip/hip_bf16.h>
#include <stdint.h>
#include <stddef.h>

typedef short bf16x8 __attribute__((ext_vector_type(8)));
typedef short s16x4 __attribute__((ext_vector_type(4)));
typedef float f32x4 __attribute__((ext_vector_type(4)));

#define HW 4096
#define WDIM 64

__device__ __forceinline__ short f2bf(float f) {
  union { __hip_bfloat16 b; short s; } u;
  u.b = __float2bfloat16(f);
  return u.s;
}
__device__ __forceinline__ float bf2f(short s) {
  union { unsigned u; float f; } u;
  u.u = ((unsigned)(unsigned short)s) << 16;
  return u.f;
}

// ---------------- prep: gather/convert weights (hi/lo split) + bias ----------------
__global__ void prep_weights(const float* __restrict__ w0, const float* __restrict__ w1,
                             const float* __restrict__ w2, const float* __restrict__ b0,
                             const float* __restrict__ b1, const float* __restrict__ b2,
                             const float* __restrict__ pw,
                             short* __restrict__ Wh, short* __restrict__ Wl,
                             short* __restrict__ Ph, short* __restrict__ Pl,
                             float* __restrict__ bias_sel) {
  int idx = blockIdx.x * 256 + threadIdx.x;
  if (idx < 768 * 256) {
    int j = idx >> 8;
    int h = (j & 255) >> 5;
    const float* w = (h < 4) ? w0 : ((h < 7) ? w1 : w2);
    float v = w[idx];
    short hi = f2bf(v);
    Wh[idx] = hi;
    Wl[idx] = f2bf(v - bf2f(hi));
  } else if (idx < 768 * 256 + 256 * 256) {
    int k = idx - 768 * 256;
    float v = pw[k];
    short hi = f2bf(v);
    Ph[k] = hi;
    Pl[k] = f2bf(v - bf2f(hi));
  } else if (idx < 768 * 256 + 256 * 256 + 768) {
    int j = idx - (768 * 256 + 256 * 256);
    int h = (j & 255) >> 5;
    const float* bb = (h < 4) ? b0 : ((h < 7) ? b1 : b2);
    bias_sel[j] = bb[j];
  }
}

// ---------------- transpose x: (B,256,HW) f32 -> XT (B,HW,256) bf16 hi/lo ----------------
__global__ void transpose_x(const float* __restrict__ x, short* __restrict__ XTh,
                            short* __restrict__ XTl) {
  __shared__ float tile[32][33];
  int b = blockIdx.z;
  int p0 = blockIdx.x * 32, c0 = blockIdx.y * 32;
  int tx = threadIdx.x, ty = threadIdx.y;       // 32 x 8
  const float* xb = x + (size_t)b * 256 * HW;
  #pragma unroll
  for (int i = 0; i < 32; i += 8)
    tile[ty + i][tx] = xb[(size_t)(c0 + ty + i) * HW + p0 + tx];
  __syncthreads();
  size_t ob = (size_t)b * HW * 256;
  #pragma unroll
  for (int i = 0; i < 32; i += 8) {
    float v = tile[tx][ty + i];
    short hi = f2bf(v);
    size_t o = ob + (size_t)(p0 + ty + i) * 256 + c0 + tx;
    XTh[o] = hi;
    XTl[o] = f2bf(v - bf2f(hi));
  }
}

// ---------------- split-bf16 MFMA GEMM, tile-parameterized ----------------
// C[b][m][p] = sum_c A[m,c]*Bm[b][p][c] + bias[m]; 3 MFMAs (hh+hl+lh).
// OUT=0: write qkv_t layout [b][t(3)][h(8)][p(4096)][d(32)] fp32 (float4 stores)
// OUT=1: write standard C[b][m][p] fp32
// 256 threads = 4 waves as 2x2 of (BM/2)x(BN/2).
template <int BM, int BN, int OUT>
__global__ __launch_bounds__(256) void gemm_split(
    const short* __restrict__ Ah, const short* __restrict__ Al,
    const short* __restrict__ Bh, const short* __restrict__ Bl,
    const float* __restrict__ bias, float* __restrict__ C, int M) {
  constexpr int LD = 40;
  constexpr int AL = BM / 64, BL = BN / 64;     // bf16x8 loads per thread
  constexpr int WM = BM / 2, WN = BN / 2;
  constexpr int MR = WM / 16, NR = WN / 16;
  __shared__ short Ash[BM * LD], Asl[BM * LD], Bsh[BN * LD], Bsl[BN * LD];
  int tid = threadIdx.x;
  int b = blockIdx.z;
  size_t aoff = (size_t)blockIdx.y * BM * 256;
  size_t boff = (size_t)b * HW * 256 + (size_t)blockIdx.x * BN * 256;
  int lane = tid & 63, wid = tid >> 6;
  int wm = wid >> 1, wn = wid & 1;
  int il = lane & 15, kg = lane >> 4;
  f32x4 acc[MR][NR] = {};
  int row_s = tid >> 2;                          // 0..63
  int kk_s = (tid & 3) * 8;                      // 0,8,16,24

  for (int kt = 0; kt < 256; kt += 32) {
    bf16x8 rah[AL], ral[AL], rbh[BL], rbl[BL];
    #pragma unroll
    for (int i = 0; i < AL; ++i) {
      size_t g = aoff + (size_t)(row_s + 64 * i) * 256 + kt + kk_s;
      rah[i] = *(const bf16x8*)&Ah[g];
      ral[i] = *(const bf16x8*)&Al[g];
    }
    #pragma unroll
    for (int i = 0; i < BL; ++i) {
      size_t g = boff + (size_t)(row_s + 64 * i) * 256 + kt + kk_s;
      rbh[i] = *(const bf16x8*)&Bh[g];
      rbl[i] = *(const bf16x8*)&Bl[g];
    }
    __syncthreads();
    #pragma unroll
    for (int i = 0; i < AL; ++i) {
      *(bf16x8*)&Ash[(row_s + 64 * i) * LD + kk_s] = rah[i];
      *(bf16x8*)&Asl[(row_s + 64 * i) * LD + kk_s] = ral[i];
    }
    #pragma unroll
    for (int i = 0; i < BL; ++i) {
      *(bf16x8*)&Bsh[(row_s + 64 * i) * LD + kk_s] = rbh[i];
      *(bf16x8*)&Bsl[(row_s + 64 * i) * LD + kk_s] = rbl[i];
    }
    __syncthreads();
    bf16x8 afh[MR], afl[MR], bfh[NR], bfl[NR];
    #pragma unroll
    for (int mr = 0; mr < MR; ++mr) {
      int r = (wm * WM + mr * 16 + il) * LD + kg * 8;
      afh[mr] = *(bf16x8*)&Ash[r];
      afl[mr] = *(bf16x8*)&Asl[r];
    }
    #pragma unroll
    for (int nr = 0; nr < NR; ++nr) {
      int r = (wn * WN + nr * 16 + il) * LD + kg * 8;
      bfh[nr] = *(bf16x8*)&Bsh[r];
      bfl[nr] = *(bf16x8*)&Bsl[r];
    }
    #pragma unroll
    for (int mr = 0; mr < MR; ++mr)
      #pragma unroll
      for (int nr = 0; nr < NR; ++nr) {
        acc[mr][nr] = __builtin_amdgcn_mfma_f32_16x16x32_bf16(afh[mr], bfh[nr], acc[mr][nr], 0, 0, 0);
        acc[mr][nr] = __builtin_amdgcn_mfma_f32_16x16x32_bf16(afh[mr], bfl[nr], acc[mr][nr], 0, 0, 0);
        acc[mr][nr] = __builtin_amdgcn_mfma_f32_16x16x32_bf16(afl[mr], bfh[nr], acc[mr][nr], 0, 0, 0);
      }
  }

  int m0 = blockIdx.y * BM, n0 = blockIdx.x * BN;
  #pragma unroll
  for (int mr = 0; mr < MR; ++mr) {
    #pragma unroll
    for (int nr = 0; nr < NR; ++nr) {
      int grow0 = m0 + wm * WM + mr * 16 + kg * 4;
      int gcol = n0 + wn * WN + nr * 16 + il;
      if (OUT == 0) {
        // qkv_t: [(b*3+t)*8+h][p][d], float4 at (grow0..+3, gcol)
        int t = grow0 >> 8, h = (grow0 >> 5) & 7, d0 = grow0 & 31;
        size_t base = (((size_t)(b * 3 + t) * 8 + h) << 17) + ((size_t)gcol << 5) + d0;
        f32x4 vv;
        #pragma unroll
        for (int r = 0; r < 4; ++r) vv[r] = acc[mr][nr][r] + bias[grow0 + r];
        *(f32x4*)&C[base] = vv;
      } else {
        size_t cbase = (size_t)b * M * HW;
        #pragma unroll
        for (int r = 0; r < 4; ++r)
          C[cbase + (size_t)(grow0 + r) * HW + gcol] = acc[mr][nr][r] + bias[grow0 + r];
      }
    }
  }
}

// ---------------- attention: d-split x8, branch-free, pipelined ----------------
// qkv_t layout: [(b*3+t)*8+h][p][d=32] fp32. Lane = pl(0..7) + 8*dq(0..7).
// Each lane owns a 4-float d-slice of one position. Logit reduced over the 8
// dq-lanes via 3 shfl_xor. All loads unconditional (OOB -> self row, masked).
template <int KSZ, int DIL>
__device__ __forceinline__ void attn_wave(const float* __restrict__ qkvt,
                                          short* __restrict__ Yh, short* __restrict__ Yl,
                                          int b, int hq, int p0, int lane) {
  constexpr int R = KSZ / 2;
  const float SCALE = 0.17677669529663687f;     // 32^-0.5
  int pl = lane & 7;
  int dq = lane >> 3;                            // 0..7
  int p = p0 + pl;
  const float* qp = qkvt + (((size_t)(b * 24 + hq)) << 17) + ((size_t)p << 5) + dq * 4;
  const float* kb = qkvt + (((size_t)(b * 24 + 8 + hq)) << 17) + dq * 4;
  const float* vb = qkvt + (((size_t)(b * 24 + 16 + hq)) << 17) + dq * 4;

  f32x4 q = *(const f32x4*)qp;
  #pragma unroll
  for (int j = 0; j < 4; ++j) q[j] *= SCALE;

  f32x4 acc = {0.f, 0.f, 0.f, 0.f};
  float denom = 0.f;
  int y = p >> 6, x = p & 63;

  #pragma unroll
  for (int dy = -R; dy <= R; ++dy) {
    #pragma unroll
    for (int dx = -R; dx <= R; ++dx) {
      int ny = y + dy * DIL;                     // wave-uniform (p0 % 8 == 0, row-aligned)
      int nx = x + dx * DIL;
      bool valid = ((unsigned)ny < WDIM) & ((unsigned)nx < WDIM);
      int pp = valid ? (ny * WDIM + nx) : p;     // always in-bounds -> unconditional loads
      f32x4 kk = *(const f32x4*)(kb + ((size_t)pp << 5));
      f32x4 vv = *(const f32x4*)(vb + ((size_t)pp << 5));
      float s = q[0] * kk[0] + q[1] * kk[1] + q[2] * kk[2] + q[3] * kk[3];
      s += __shfl_xor(s, 8);
      s += __shfl_xor(s, 16);
      s += __shfl_xor(s, 32);                    // all lanes hold full dot
      float e = __expf(valid ? s : 0.0f);        // OOB contributes exp(0)=1 to denom
      denom += e;
      float en = valid ? e : 0.0f;               // ...and 0 to numerator
      #pragma unroll
      for (int j = 0; j < 4; ++j) acc[j] += en * vv[j];
    }
  }

  float inv = 1.0f / denom;
  size_t yo = ((size_t)b * HW + p) * 256 + hq * 32 + dq * 4;
  s16x4 oh, ol;
  #pragma unroll
  for (int j = 0; j < 4; ++j) {
    float v = acc[j] * inv;
    short hi = f2bf(v);
    oh[j] = hi;
    ol[j] = f2bf(v - bf2f(hi));
  }
  *(s16x4*)&Yh[yo] = oh;                         // 8B-aligned
  *(s16x4*)&Yl[yo] = ol;
}

// waves (global id gw, 8192 total): [0,4096) ksz5 h0-3, [4096,7168) ksz7 h4-6,
// [7168,8192) ksz9 h7. Each wave: 8 positions. 2048 blocks x 4 waves.
__global__ __launch_bounds__(256, 8) void attn_all(const float* __restrict__ qkvt,
                                                   short* __restrict__ Yh,
                                                   short* __restrict__ Yl) {
  int tid = threadIdx.x;
  int lane = tid & 63, wave = tid >> 6;
  int gw = blockIdx.x * 4 + wave;
  if (gw < 4096) {
    int tile = gw & 511;
    int t2 = gw >> 9;
    int b = t2 & 1, h = t2 >> 1;                 // h 0..3
    attn_wave<5, 1>(qkvt, Yh, Yl, b, h, tile * 8, lane);
  } else if (gw < 7168) {
    int s = gw - 4096;
    int tile = s & 511;
    int t2 = s >> 9;
    int b = t2 & 1, h = 4 + (t2 >> 1);           // h 4..6
    attn_wave<7, 2>(qkvt, Yh, Yl, b, h, tile * 8, lane);
  } else {
    int s = gw - 7168;
    int tile = s & 511;
    int b = s >> 9;                              // h = 7
    attn_wave<9, 3>(qkvt, Yh, Yl, b, 7, tile * 8, lane);
  }
}

// ---------------- launch ----------------
extern "C" void kernel_launch(void* const* d_in, const int* in_sizes, int n_in,
                              void* d_out, int out_size, void* d_ws, size_t ws_size,
                              hipStream_t stream) {
  const float* x  = (const float*)d_in[0];
  const float* w0 = (const float*)d_in[1];
  const float* b0 = (const float*)d_in[2];
  const float* w1 = (const float*)d_in[3];
  const float* b1 = (const float*)d_in[4];
  const float* w2 = (const float*)d_in[5];
  const float* b2 = (const float*)d_in[6];
  const float* pw = (const float*)d_in[7];
  const float* pb = (const float*)d_in[8];

  char* ws = (char*)d_ws;
  float* qkvt = (float*)ws; ws += (size_t)2 * 768 * HW * 4;   // [b][t][h][p][d]
  short* XTh = (short*)ws;  ws += (size_t)2 * HW * 256 * 2;
  short* XTl = (short*)ws;  ws += (size_t)2 * HW * 256 * 2;
  short* Yh  = (short*)ws;  ws += (size_t)2 * HW * 256 * 2;
  short* Yl  = (short*)ws;  ws += (size_t)2 * HW * 256 * 2;
  short* Wh  = (short*)ws;  ws += (size_t)768 * 256 * 2;
  short* Wl  = (short*)ws;  ws += (size_t)768 * 256 * 2;
  short* Ph  = (short*)ws;  ws += (size_t)256 * 256 * 2;
  short* Pl  = (short*)ws;  ws += (size_t)256 * 256 * 2;
  float* bsel= (float*)ws;  ws += 4096;

  prep_weights<<<1027, 256, 0, stream>>>(w0, w1, w2, b0, b1, b2, pw, Wh, Wl, Ph, Pl, bsel);
  transpose_x<<<dim3(128, 8, 2), dim3(32, 8), 0, stream>>>(x, XTh, XTl);
  gemm_split<64, 128, 0><<<dim3(32, 12, 2), 256, 0, stream>>>(Wh, Wl, XTh, XTl, bsel, qkvt, 768);
  attn_all<<<2048, 256, 0, stream>>>(qkvt, Yh, Yl);
  gemm_split<64, 64, 1><<<dim3(64, 4, 2), 256, 0, stream>>>(Ph, Pl, Yh, Yl, pb, (float*)d_out, 256);
}